// Round 18
// baseline (306.889 us; speedup 1.0000x reference)
//
#include <hip/hip_runtime.h>
#include <hip/hip_bf16.h>
#include <float.h>

#define B_ 4
#define N_ 1024
#define H_ 16
#define DH_ 64
#define NM_ 4
#define J_ 1028          // N_ + NM_
#define IT_ 4            // i rows per attention block
#define TOPK_ 64
#define QKSCALE 10.0f
// fragment-ordered K: ktF[bg][jt(66)][f(2)][l(64)][e(8)]  halves; per-bg = 66*1024 = 67584
// fragment-ordered V^T: vtF[bg][dc(4)][jtE(33)][l(64)][e(8)]; per-bg = 4*33*512 = 67584
#define KTF_BG 67584
#define VTF_DC 16896     // 33*512

typedef __attribute__((ext_vector_type(8))) short short8;
typedef __attribute__((ext_vector_type(4))) float f32x4;
typedef __attribute__((ext_vector_type(8))) unsigned short ushort8;
typedef __attribute__((ext_vector_type(4))) unsigned int u32x4;
typedef __attribute__((ext_vector_type(2))) unsigned int u32x2;
typedef _Float16 half8 __attribute__((ext_vector_type(8)));

__device__ __forceinline__ unsigned short f2b(float f){
  union { float f; unsigned int i; } c; c.f = f;
  unsigned int r = c.i + 0x7FFFu + ((c.i >> 16) & 1u);   // RNE
  return (unsigned short)(r >> 16);
}
__device__ __forceinline__ unsigned short f2h(float f){
  return __builtin_bit_cast(unsigned short, (_Float16)f);
}
__device__ __forceinline__ float h2f(unsigned short u){
  return (float)__builtin_bit_cast(_Float16, u);
}
__device__ __forceinline__ unsigned int h2key(unsigned int u){
  return (u & 0x8000u) ? (~u & 0xFFFFu) : (u | 0x8000u);
}
__device__ __forceinline__ float key2f(unsigned int k){
  unsigned int u = (k & 0x8000u) ? (k & 0x7FFFu) : (~k & 0xFFFFu);
  return h2f((unsigned short)u);
}

// ---- fused prep: weight TRANSPOSE+convert (bf16 [n][k]), x convert, memory-slot seed ----
__global__ __launch_bounds__(256) void k_cvtAll(
    const float* __restrict__ x,  const float* __restrict__ wq,
    const float* __restrict__ wk, const float* __restrict__ wv,
    const float* __restrict__ wg, const float* __restrict__ wo,
    unsigned short* __restrict__ xb, unsigned short* __restrict__ wcatT,
    unsigned short* __restrict__ wobT,
    const float* __restrict__ mk, const float* __restrict__ mv,
    unsigned short* __restrict__ ktF, unsigned short* __restrict__ vtF){
  const int t = threadIdx.x;
  const unsigned bid = blockIdx.x;
  if (bid < 1280){
    // ---- weight transpose: 64x64 tile, src [k][n] f32 -> dst [n][k] bf16 ----
    __shared__ unsigned short tile[64][70];
    const int which = bid >> 8;          // 0..4 (q,k,v,g,o)
    const int tl = bid & 255;
    const int tr = tl >> 4, tc = tl & 15;   // k-tile, n-tile
    const float* src = which == 0 ? wq : which == 1 ? wk : which == 2 ? wv : which == 3 ? wg : wo;
    {
      int r = t >> 2, c0 = (t & 3) * 16;
      const float* sp = src + (size_t)(tr * 64 + r) * 1024 + tc * 64 + c0;
      #pragma unroll
      for (int e = 0; e < 16; ++e) tile[r][c0 + e] = f2b(sp[e]);
    }
    __syncthreads();
    {
      int rn = t >> 2, k0 = (t & 3) * 16;
      int n = tc * 64 + rn;
      unsigned short* dp = (which == 4)
        ? wobT + (size_t)n * 1024 + tr * 64 + k0
        : wcatT + ((size_t)which * 1024 + n) * 1024 + tr * 64 + k0;
      ushort8 v0, v1;
      #pragma unroll
      for (int e = 0; e < 8; ++e) v0[e] = tile[k0 + e][rn];
      #pragma unroll
      for (int e = 0; e < 8; ++e) v1[e] = tile[k0 + 8 + e][rn];
      *(ushort8*)dp = v0;
      *(ushort8*)(dp + 8) = v1;
    }
    return;
  }
  if (bid >= 1280 && bid < 1284){
    // ---- memory-slot prep: normalize mem_k, seed slots, zero pad tiles ----
    int h = (bid - 1280) * 4 + (t >> 6);   // 0..15
    int d = t & 63;
    unsigned short kh[4], vh[4];
    #pragma unroll
    for (int mm = 0; mm < 4; ++mm){
      float kv = mk[(h * 4 + mm) * 64 + d];
      float ss = kv * kv;
      #pragma unroll
      for (int off = 32; off; off >>= 1) ss += __shfl_xor(ss, off);
      kh[mm] = f2h(kv / fmaxf(sqrtf(ss), 1e-12f));
      vh[mm] = f2h(mv[(h * 4 + mm) * 64 + d]);
    }
    for (int b = 0; b < B_; ++b){
      int bg = b * 16 + h;
      #pragma unroll
      for (int mm = 0; mm < 4; ++mm)
        ktF[(size_t)bg * KTF_BG + (size_t)(d >> 5) * 512 + (mm + ((d >> 3) & 3) * 16) * 8 + (d & 7)] = kh[mm];
      #pragma unroll
      for (int mm = 0; mm < 4; ++mm)
        vtF[(size_t)bg * KTF_BG + (size_t)(d >> 4) * VTF_DC + (d & 15) * 8 + mm] = vh[mm];
      {
        unsigned int* kz = (unsigned int*)(ktF + (size_t)bg * KTF_BG + 64 * 1024);
        for (int c = d; c < 1024; c += 64) kz[c] = 0u;
      }
      #pragma unroll
      for (int dc = 0; dc < 4; ++dc){
        unsigned int* vz = (unsigned int*)(vtF + (size_t)bg * KTF_BG + (size_t)dc * VTF_DC + 32 * 512);
        for (int c = d; c < 256; c += 64) vz[c] = 0u;
      }
    }
    return;
  }
  // ---- x convert ----
  int i = (bid - 1284) * 256 + t;
  const int st = (3072 - 1284) * 256;
  for (; i < 4096 * 1024; i += st) xb[i] = f2b(x[i]);
}

// ---------------- fused QKVG GEMM: 4096x4096x1024 (wcatT [n][k]), 128x128 tile, BK=64 ----------------
__global__ __launch_bounds__(256) void k_gemmF(const unsigned short* __restrict__ A,
                                               const unsigned short* __restrict__ WcT,
                                               unsigned short* __restrict__ qn,
                                               unsigned short* __restrict__ ktF,
                                               unsigned short* __restrict__ vtF,
                                               unsigned short* __restrict__ gate,
                                               const float* __restrict__ bgv)
{
  __shared__ unsigned short As[128][72];
  __shared__ unsigned short Bs[128][72];
  const int t = threadIdx.x;
  const int m0 = blockIdx.y * 128, n0 = blockIdx.x * 128;
  const int l = t & 63, w = t >> 6, wr = w >> 1, wc = w & 1;
  const int l15 = l & 15, l4 = l >> 4;

  f32x4 acc[4][4];
  #pragma unroll
  for (int a = 0; a < 4; ++a)
    #pragma unroll
    for (int b2 = 0; b2 < 4; ++b2) acc[a][b2] = (f32x4){0.f, 0.f, 0.f, 0.f};

  for (int k0 = 0; k0 < 1024; k0 += 64){
    #pragma unroll
    for (int cc = 0; cc < 4; ++cc){          // A tile: 128x64
      int c = t + cc * 256;
      int row = c >> 3, colc = (c & 7) * 8;
      *(ushort8*)&As[row][colc] = *(const ushort8*)&A[(m0 + row) * 1024 + k0 + colc];
    }
    #pragma unroll
    for (int cc = 0; cc < 4; ++cc){          // B tile: 128n x 64k, direct row copy
      int c = t + cc * 256;
      int row = c >> 3, colc = (c & 7) * 8;
      *(ushort8*)&Bs[row][colc] = *(const ushort8*)&WcT[(size_t)(n0 + row) * 1024 + k0 + colc];
    }
    __syncthreads();
    #pragma unroll
    for (int ks = 0; ks < 64; ks += 32){
      short8 af[4], bfr[4];
      #pragma unroll
      for (int mf = 0; mf < 4; ++mf) af[mf]  = *(const short8*)&As[wr * 64 + mf * 16 + l15][ks + l4 * 8];
      #pragma unroll
      for (int nf = 0; nf < 4; ++nf) bfr[nf] = *(const short8*)&Bs[wc * 64 + nf * 16 + l15][ks + l4 * 8];
      #pragma unroll
      for (int mf = 0; mf < 4; ++mf)
        #pragma unroll
        for (int nf = 0; nf < 4; ++nf)
          acc[mf][nf] = __builtin_amdgcn_mfma_f32_16x16x32_bf16(af[mf], bfr[nf], acc[mf][nf], 0, 0, 0);
    }
    __syncthreads();
  }

  const int which = n0 >> 10;        // 0=q 1=k 2=v 3=gate (uniform per block; 128-tile never straddles)
  const int ncol0 = (n0 & 1023) + wc * 64;
  const int hcol = ncol0 >> 6;
  #pragma unroll
  for (int mf = 0; mf < 4; ++mf){
    if (which == 2){
      int row0 = m0 + wr * 64 + mf * 16 + l4 * 4;
      int bb = row0 >> 10;
      int j0 = (row0 & 1023) + NM_;
      int jtE = j0 >> 5, lj = (j0 & 31) >> 3, e0 = j0 & 7;
      #pragma unroll
      for (int nf = 0; nf < 4; ++nf){
        int col = ncol0 + nf * 16 + l15;
        int h = col >> 6, d = col & 63;
        unsigned int lo = (unsigned int)f2h(acc[mf][nf][0]) | ((unsigned int)f2h(acc[mf][nf][1]) << 16);
        unsigned int hi = (unsigned int)f2h(acc[mf][nf][2]) | ((unsigned int)f2h(acc[mf][nf][3]) << 16);
        unsigned short* dst = vtF + (size_t)(bb * 16 + h) * KTF_BG +
                              (size_t)(d >> 4) * VTF_DC + (size_t)jtE * 512 +
                              ((d & 15) + lj * 16) * 8 + e0;
        *(u32x2*)dst = (u32x2){lo, hi};
      }
    } else {
      #pragma unroll
      for (int r = 0; r < 4; ++r){
        int row = m0 + wr * 64 + mf * 16 + l4 * 4 + r;
        float rn = 1.f;
        if (which <= 1){
          float ss = 0.f;
          #pragma unroll
          for (int nf = 0; nf < 4; ++nf) ss += acc[mf][nf][r] * acc[mf][nf][r];
          #pragma unroll
          for (int off = 1; off < 16; off <<= 1) ss += __shfl_xor(ss, off);
          rn = 1.f / fmaxf(sqrtf(ss), 1e-12f);
          if (which == 0) rn *= QKSCALE;
        }
        #pragma unroll
        for (int nf = 0; nf < 4; ++nf){
          int col = ncol0 + nf * 16 + l15;
          float v = acc[mf][nf][r];
          int bb = row >> 10, ii = row & 1023;
          if (which == 3){
            float g = v + bgv[3 * 1024 + col];
            gate[(size_t)row * 1024 + col] = f2h(1.f / (1.f + __expf(-g)));
          } else if (which == 0){
            int d = col & 63;
            qn[((size_t)(bb * H_ + hcol) * N_ + ii) * DH_ + d] = f2h(v * rn);
          } else { // which == 1: K -> ktF fragment order
            int j = ii + NM_;
            int d = col & 63;
            ktF[(size_t)(bb * 16 + hcol) * KTF_BG + (size_t)(j >> 4) * 1024 +
                (size_t)(d >> 5) * 512 + ((j & 15) + ((d >> 3) & 3) * 16) * 8 + (d & 7)]
              = f2h(v * rn);
          }
        }
      }
    }
  }
}

// ---------------- final GEMM aout x WoT -> f32 out, 128x128 tile, BK=64 ----------------
__global__ __launch_bounds__(256) void k_gemmO(const unsigned short* __restrict__ A,
                                               const unsigned short* __restrict__ WT,
                                               float* __restrict__ outp)
{
  __shared__ unsigned short As[128][72];
  __shared__ unsigned short Bs[128][72];
  const int t = threadIdx.x;
  const int m0 = blockIdx.y * 128, n0 = blockIdx.x * 128;
  const int l = t & 63, w = t >> 6, wr = w >> 1, wc = w & 1;
  const int l15 = l & 15, l4 = l >> 4;

  f32x4 acc[4][4];
  #pragma unroll
  for (int a = 0; a < 4; ++a)
    #pragma unroll
    for (int b2 = 0; b2 < 4; ++b2) acc[a][b2] = (f32x4){0.f, 0.f, 0.f, 0.f};

  for (int k0 = 0; k0 < 1024; k0 += 64){
    #pragma unroll
    for (int cc = 0; cc < 4; ++cc){
      int c = t + cc * 256;
      int row = c >> 3, colc = (c & 7) * 8;
      *(ushort8*)&As[row][colc] = *(const ushort8*)&A[(m0 + row) * 1024 + k0 + colc];
    }
    #pragma unroll
    for (int cc = 0; cc < 4; ++cc){
      int c = t + cc * 256;
      int row = c >> 3, colc = (c & 7) * 8;
      *(ushort8*)&Bs[row][colc] = *(const ushort8*)&WT[(size_t)(n0 + row) * 1024 + k0 + colc];
    }
    __syncthreads();
    #pragma unroll
    for (int ks = 0; ks < 64; ks += 32){
      short8 af[4], bfr[4];
      #pragma unroll
      for (int mf = 0; mf < 4; ++mf) af[mf]  = *(const short8*)&As[wr * 64 + mf * 16 + l15][ks + l4 * 8];
      #pragma unroll
      for (int nf = 0; nf < 4; ++nf) bfr[nf] = *(const short8*)&Bs[wc * 64 + nf * 16 + l15][ks + l4 * 8];
      #pragma unroll
      for (int mf = 0; mf < 4; ++mf)
        #pragma unroll
        for (int nf = 0; nf < 4; ++nf)
          acc[mf][nf] = __builtin_amdgcn_mfma_f32_16x16x32_bf16(af[mf], bfr[nf], acc[mf][nf], 0, 0, 0);
    }
    __syncthreads();
  }

  #pragma unroll
  for (int mf = 0; mf < 4; ++mf)
    #pragma unroll
    for (int r = 0; r < 4; ++r){
      int row = m0 + wr * 64 + mf * 16 + l4 * 4 + r;
      #pragma unroll
      for (int nf = 0; nf < 4; ++nf)
        outp[(size_t)row * 1024 + n0 + wc * 64 + nf * 16 + l15] = acc[mf][nf][r];
    }
}

// ---------------- fused attention, all-MFMA, pipelined A/E, LDS-tiered ----------------
// NJTE_MAX 33: it 128..255 (~146KB LDS, 1 blk/CU, MINW=4 -> 128 VGPR cap, A+B fused, DEPTH=4)
// NJTE_MAX 17: it 0..127   (~81KB, 2 blk/CU, MINW=8 -> 64 VGPR cap, separate B, DEPTH=2)
template<int NJTE_MAX, int MINW, bool FUSE_AB, int DEPTH>
__global__ __launch_bounds__(1024, MINW) void k_attnM(
  const unsigned short* __restrict__ qn, const unsigned short* __restrict__ ktF,
  const unsigned short* __restrict__ vtF, const float* __restrict__ wpre,
  const float* __restrict__ wpost, const float* __restrict__ hsc,
  const unsigned short* __restrict__ gate, unsigned short* __restrict__ aout,
  int itBase)
{
  constexpr int JSTT = NJTE_MAX * 32 + 8;      // sd row stride (halves)
  constexpr int NG = (JSTT + 127) / 128;       // phase-C 128-col groups
  __shared__ unsigned short sd[16 * IT_ * JSTT];
  __shared__ unsigned short qls[16 * 4 * 64];
  __shared__ unsigned short wpre16[16 * 32];
  __shared__ unsigned short wpost16[16 * 32];

  const int blk = blockIdx.x;
  const int b = (blk >> 1) & 3;                  // fixed per XCD pair (blk%8 -> XCD)
  const int idx = ((blk >> 3) << 1) | (blk & 1); // 0..127 within tier
  const int it = itBase - idx;                   // big tiles first within tier
  const int i0 = it * IT_;
  const int nAmax = i0 + IT_ + 4;
  const int nJtA = (nAmax + 15) >> 4;
  const int nJtE = (nAmax + 31) >> 5;
  const int nJtD = nJtE * 2;
  const int jc = nJtE * 32;            // processing bound for phase C
  const int t = threadIdx.x;
  const int w = t >> 6, l = t & 63;
  const int l15 = l & 15, l4 = l >> 4;

  if (t < 256){
    int h = t >> 4, g = t & 15;
    wpre16[h * 32 + g]       = f2h(wpre[h * 16 + g]);
    wpre16[h * 32 + 16 + g]  = 0;
    wpost16[h * 32 + g]      = f2h(wpost[h * 16 + g]);
    wpost16[h * 32 + 16 + g] = 0;
  }
  for (int c = t; c < 2048; c += 1024){
    int d2 = c & 31, ii = (c >> 5) & 3, g = c >> 7;
    ((unsigned int*)qls)[c] =
      *(const unsigned int*)(qn + ((size_t)(b * 16 + g) * N_ + i0 + ii) * 64 + d2 * 2);
  }
  __syncthreads();

  // ---- phase A: raw dots, software-pipelined (DEPTH tasks in flight); FUSE_AB: premix per-jt ----
  {
    half8 wa = *(const half8*)&wpre16[l15 * 32 + l4 * 8];
    const int nw16 = (nJtA > w) ? ((nJtA - w + 15) >> 4) : 0;
    const int ntask = nw16 * 16;
    if (ntask > 0){
      const int tmax = ntask - 1;
      const unsigned short* kl = ktF + (size_t)(b * 16) * KTF_BG + (size_t)l * 8;
      auto kp = [&](int task)->const unsigned short*{
        int tt = task > tmax ? tmax : task;
        int g = tt & 15, jti = tt >> 4;
        return kl + (size_t)g * KTF_BG + (((size_t)(w + jti * 16)) << 10);
      };
      half8 k0a, k0b, k1a, k1b, k2a, k2b, k3a, k3b;
      { const unsigned short* p = kp(0); k0a = *(const half8*)p; k0b = *(const half8*)(p + 512); }
      { const unsigned short* p = kp(1); k1a = *(const half8*)p; k1b = *(const half8*)(p + 512); }
      if (DEPTH >= 4){
        const unsigned short* p2 = kp(2); k2a = *(const half8*)p2; k2b = *(const half8*)(p2 + 512);
        const unsigned short* p3 = kp(3); k3a = *(const half8*)p3; k3b = *(const half8*)(p3 + 512);
      }
      for (int task = 0; task < ntask; task += 2){
        half8 cA0 = k0a, cA1 = k0b, cB0 = k1a, cB1 = k1b;
        if (DEPTH >= 4){
          k0a = k2a; k0b = k2b; k1a = k3a; k1b = k3b;
          const unsigned short* pa = kp(task + 4);
          const unsigned short* pb = kp(task + 5);
          k2a = *(const half8*)pa; k2b = *(const half8*)(pa + 512);
          k3a = *(const half8*)pb; k3b = *(const half8*)(pb + 512);
        } else {
          const unsigned short* pa = kp(task + 2);
          const unsigned short* pb = kp(task + 3);
          k0a = *(const half8*)pa; k0b = *(const half8*)(pa + 512);
          k1a = *(const half8*)pb; k1b = *(const half8*)(pb + 512);
        }
        #pragma unroll
        for (int s = 0; s < 2; ++s){
          const int tt = task + s;
          const int g = tt & 15, jt = w + ((tt >> 4) << 4);
          const unsigned short* qp = &qls[(g * 4 + (l15 & 3)) * 64 + l4 * 8];
          half8 qf0 = *(const half8*)(qp);
          half8 qf1 = *(const half8*)(qp + 32);
          f32x4 acc = (f32x4){0.f, 0.f, 0.f, 0.f};
          acc = __builtin_amdgcn_mfma_f32_16x16x32_f16(s ? cB0 : cA0, qf0, acc, 0, 0, 0);
          acc = __builtin_amdgcn_mfma_f32_16x16x32_f16(s ? cB1 : cA1, qf1, acc, 0, 0, 0);
          if (l15 < IT_){
            unsigned int pk0 = (unsigned int)f2h(acc[0]) | ((unsigned int)f2h(acc[1]) << 16);
            unsigned int pk1 = (unsigned int)f2h(acc[2]) | ((unsigned int)f2h(acc[3]) << 16);
            unsigned int* dst = (unsigned int*)&sd[(g * IT_ + l15) * JSTT + jt * 16 + l4 * 4];
            dst[0] = pk0; dst[1] = pk1;
          }
        }
        if constexpr (FUSE_AB){
          if ((task & 15) == 14){
            // all 16 g of this jt written by THIS wave; premix in place, no barrier
            const int jt = w + ((task >> 4) << 4);
            asm volatile("s_waitcnt lgkmcnt(0)" ::: "memory");
            #pragma unroll
            for (int ii = 0; ii < IT_; ++ii){
              unsigned int fb[4] = {0u, 0u, 0u, 0u};
              if (l4 < 2){
                const unsigned short* src = &sd[((l4 * 8) * IT_ + ii) * JSTT + jt * 16 + l15];
                #pragma unroll
                for (int e = 0; e < 8; e += 2){
                  unsigned int lo = src[(size_t)(e)     * IT_ * JSTT];
                  unsigned int hi = src[(size_t)(e + 1) * IT_ * JSTT];
                  fb[e >> 1] = (lo & 0xFFFFu) | (hi << 16);
                }
              }
              f32x4 pacc = (f32x4){0.f, 0.f, 0.f, 0.f};
              pacc = __builtin_amdgcn_mfma_f32_16x16x32_f16(wa, __builtin_bit_cast(half8, *(u32x4*)fb), pacc, 0, 0, 0);
              asm volatile("s_waitcnt lgkmcnt(0)" ::: "memory");
              #pragma unroll
              for (int r = 0; r < 4; ++r)
                sd[((l4 * 4 + r) * IT_ + ii) * JSTT + jt * 16 + l15] = f2h(pacc[r]);
            }
          }
        }
      }
    }
    __syncthreads();
    if constexpr (!FUSE_AB){
      // ---- phase B: W_pre premix via MFMA, task loop ----
      const int ntaskB = IT_ * nJtA;
      for (int task = w; task < ntaskB; task += 16){
        const int ii = task & (IT_ - 1), jt = task >> 2;
        unsigned int fb[4] = {0u, 0u, 0u, 0u};
        if (l4 < 2){
          const unsigned short* src = &sd[((l4 * 8) * IT_ + ii) * JSTT + jt * 16 + l15];
          #pragma unroll
          for (int e = 0; e < 8; e += 2){
            unsigned int lo = src[(size_t)(e)     * IT_ * JSTT];
            unsigned int hi = src[(size_t)(e + 1) * IT_ * JSTT];
            fb[e >> 1] = (lo & 0xFFFFu) | (hi << 16);
          }
        }
        f32x4 acc = (f32x4){0.f, 0.f, 0.f, 0.f};
        acc = __builtin_amdgcn_mfma_f32_16x16x32_f16(wa, __builtin_bit_cast(half8, *(u32x4*)fb), acc, 0, 0, 0);
        #pragma unroll
        for (int r = 0; r < 4; ++r)
          sd[((l4 * 4 + r) * IT_ + ii) * JSTT + jt * 16 + l15] = f2h(acc[r]);
      }
      __syncthreads();
    }
  }

  // ---- phase C: per-row top-64 threshold + softmax, causal-trimmed to jc ----
  for (int rr = 0; rr < 4; ++rr){
    const int row = w * 4 + rr;            // 0..63
    const int g = row >> 2, ii = row & 3;
    const int nA = i0 + ii + 5;
    unsigned short* rowp = &sd[(g * IT_ + ii) * JSTT];
    unsigned int kw[NG];
    #pragma unroll
    for (int grp = 0; grp < NG; ++grp){
      kw[grp] = 0u;
      if (grp * 128 < jc){
        int j = grp * 128 + l * 2;
        unsigned int u = (j < JSTT) ? *(const unsigned int*)(rowp + j) : 0u;
        unsigned int klo = h2key(u & 0xFFFFu);
        unsigned int khi = h2key(u >> 16);
        if (j     >= nA) klo = 0u;
        if (j + 1 >= nA) khi = 0u;
        kw[grp] = klo | (khi << 16);
      }
    }
    unsigned int kmx = 0u;
    #pragma unroll
    for (int grp = 0; grp < NG; ++grp){
      if (grp * 128 < jc){
        unsigned int m2 = max(kw[grp] >> 16, kw[grp] & 0xFFFFu);
        kmx = max(kmx, m2);
      }
    }
    #pragma unroll
    for (int off = 32; off; off >>= 1) kmx = max(kmx, (unsigned int)__shfl_xor((int)kmx, off));
    const float mx = key2f(kmx);

    unsigned int T = 0u;
    if (nA > TOPK_){
      for (int bit = 15; bit >= 2; --bit){
        unsigned int Tc = T | (1u << bit);
        int c = 0;
        #pragma unroll
        for (int grp = 0; grp < NG; ++grp){
          if (grp * 128 < jc){
            c += __popcll(__ballot((kw[grp] & 0xFFFFu) >= Tc));
            c += __popcll(__ballot((kw[grp] >> 16) >= Tc));
          }
        }
        if (c >= TOPK_){
          T = Tc;
          if (c == TOPK_) break;
        }
      }
    }
    if (T == 0u) T = 1u;

    float s = 0.f;
    float ev[2 * NG];
    #pragma unroll
    for (int grp = 0; grp < NG; ++grp){
      if (grp * 128 < jc){
        unsigned int klo = kw[grp] & 0xFFFFu, khi = kw[grp] >> 16;
        float elo = (klo >= T) ? __expf(key2f(klo) - mx) : 0.f;
        float ehi = (khi >= T) ? __expf(key2f(khi) - mx) : 0.f;
        ev[grp * 2] = elo; ev[grp * 2 + 1] = ehi;
        s += elo + ehi;
      }
    }
    #pragma unroll
    for (int off = 32; off; off >>= 1) s += __shfl_xor(s, off);
    float inv = 1.f / s;
    #pragma unroll
    for (int grp = 0; grp < NG; ++grp){
      if (grp * 128 < jc){
        int j = grp * 128 + l * 2;
        if (j < JSTT)
          *(unsigned int*)(rowp + j) =
            (unsigned int)f2h(ev[grp * 2] * inv) | ((unsigned int)f2h(ev[grp * 2 + 1] * inv) << 16);
      }
    }
  }
  __syncthreads();

  // ---- phase D: postmix via MFMA (causal-trimmed) ----
  {
    const int ntask = IT_ * nJtD;
    for (int task = w; task < ntask; task += 16){
      const int ii = task & (IT_ - 1), jt = task >> 2;
      half8 wa = *(const half8*)&wpost16[l15 * 32 + l4 * 8];
      unsigned int fb[4] = {0u, 0u, 0u, 0u};
      if (l4 < 2){
        const unsigned short* src = &sd[((l4 * 8) * IT_ + ii) * JSTT + jt * 16 + l15];
        #pragma unroll
        for (int e = 0; e < 8; e += 2){
          unsigned int lo = src[(size_t)(e)     * IT_ * JSTT];
          unsigned int hi = src[(size_t)(e + 1) * IT_ * JSTT];
          fb[e >> 1] = (lo & 0xFFFFu) | (hi << 16);
        }
      }
      f32x4 acc = (f32x4){0.f, 0.f, 0.f, 0.f};
      acc = __builtin_amdgcn_mfma_f32_16x16x32_f16(wa, __builtin_bit_cast(half8, *(u32x4*)fb), acc, 0, 0, 0);
      #pragma unroll
      for (int r = 0; r < 4; ++r)
        sd[((l4 * 4 + r) * IT_ + ii) * JSTT + jt * 16 + l15] = f2h(acc[r]);
    }
  }
  __syncthreads();

  // ---- phase E: PV via MFMA, software-pipelined V prefetch (DEPTH-deep) ----
  for (int task = w; task < 64; task += 16){
    const int h = task >> 2, dc = task & 3;
    const int bg = b * 16 + h;
    const unsigned short* vbase = vtF + (size_t)bg * KTF_BG + (size_t)dc * VTF_DC + (size_t)l * 8;
    const unsigned short* arow = &sd[(h * IT_ + (l15 & 3)) * JSTT + l4 * 8];
    const int jm = nJtE - 1;
    auto vp_ = [&](int jt)->const half8*{
      int tt = jt > jm ? jm : jt;
      return (const half8*)(vbase + ((size_t)tt << 9));
    };
    half8 v0 = *vp_(0), v1 = *vp_(1), v2, v3;
    if (DEPTH >= 4){ v2 = *vp_(2); v3 = *vp_(3); }
    f32x4 acc = (f32x4){0.f, 0.f, 0.f, 0.f};
    int jt = 0;
    for (; jt + 2 <= nJtE; jt += 2){
      half8 cA = v0, cB = v1;
      if (DEPTH >= 4){
        v0 = v2; v1 = v3;
        v2 = *vp_(jt + 4); v3 = *vp_(jt + 5);
      } else {
        v0 = *vp_(jt + 2); v1 = *vp_(jt + 3);
      }
      half8 af0 = *(const half8*)(arow + jt * 32);
      half8 af1 = *(const half8*)(arow + jt * 32 + 32);
      acc = __builtin_amdgcn_mfma_f32_16x16x32_f16(af0, cA, acc, 0, 0, 0);
      acc = __builtin_amdgcn_mfma_f32_16x16x32_f16(af1, cB, acc, 0, 0, 0);
    }
    if (jt < nJtE){
      half8 af0 = *(const half8*)(arow + jt * 32);
      acc = __builtin_amdgcn_mfma_f32_16x16x32_f16(af0, v0, acc, 0, 0, 0);
    }
    if (l4 == 0){
      const float hs = hsc[h];
      #pragma unroll
      for (int r = 0; r < IT_; ++r){
        const int irow = (b << 10) | (i0 + r);
        const size_t o = (size_t)irow * 1024 + h * 64 + dc * 16 + l15;
        aout[o] = f2b(acc[r] * hs * h2f(gate[o]));
      }
    }
  }
}

// ---------------- host ----------------
extern "C" void kernel_launch(void* const* d_in, const int* in_sizes, int n_in,
                              void* d_out, int out_size, void* d_ws, size_t ws_size,
                              hipStream_t stream) {
  const float* x     = (const float*)d_in[0];
  const float* Wq    = (const float*)d_in[1];
  const float* Wk    = (const float*)d_in[2];
  const float* Wv    = (const float*)d_in[3];
  const float* Wpre  = (const float*)d_in[4];
  const float* Wpost = (const float*)d_in[5];
  const float* mk    = (const float*)d_in[6];
  const float* mv    = (const float*)d_in[7];
  const float* hsc   = (const float*)d_in[8];
  const float* Wg    = (const float*)d_in[9];
  const float* bg    = (const float*)d_in[10];
  const float* Wo    = (const float*)d_in[11];
  float* out = (float*)d_out;

  char* ws = (char*)d_ws;
  size_t off = 0;
  auto alloc = [&](size_t bytes) -> void* {
    void* p = ws + off; off += (bytes + 255) & ~(size_t)255; return p;
  };
  unsigned short* xb    = (unsigned short*)alloc((size_t)4096 * 1024 * 2);
  unsigned short* wcatT = (unsigned short*)alloc((size_t)4096 * 1024 * 2);   // [n][k] bf16
  unsigned short* wobT  = (unsigned short*)alloc((size_t)1024 * 1024 * 2);   // [n][k] bf16
  unsigned short* qn    = (unsigned short*)alloc((size_t)B_ * H_ * N_ * DH_ * 2);  // f16
  unsigned short* ktF   = (unsigned short*)alloc((size_t)B_ * H_ * KTF_BG * 2);    // frag-ordered K
  unsigned short* vtF   = (unsigned short*)alloc((size_t)B_ * H_ * KTF_BG * 2);    // frag-ordered V^T
  unsigned short* gate  = (unsigned short*)alloc((size_t)4096 * 1024 * 2);         // f16
  unsigned short* aout  = (unsigned short*)alloc((size_t)4096 * 1024 * 2);         // bf16

  k_cvtAll<<<3072, 256, 0, stream>>>(x, Wq, Wk, Wv, Wg, Wo, xb, wcatT, wobT,
                                     mk, mv, ktF, vtF);

  // bg offset trick: gate epilogue indexes bgv[3*1024 + col]; pass bg - 3*1024 so it reads bg[col]
  k_gemmF<<<dim3(32, 32), 256, 0, stream>>>(xb, wcatT, qn, ktF, vtF, gate, bg - 3 * 1024);

  // big tier first (it 128..255, 1 blk/CU, A+B fused, 4-deep), then small tier (2 blk/CU, 2-deep)
  k_attnM<33, 4, true, 4><<<512, 1024, 0, stream>>>(qn, ktF, vtF, Wpre, Wpost, hsc, gate, aout, 255);
  k_attnM<17, 8, false, 2><<<512, 1024, 0, stream>>>(qn, ktF, vtF, Wpre, Wpost, hsc, gate, aout, 127);

  k_gemmO<<<dim3(8, 32), 256, 0, stream>>>(aout, wobT, out);
}